// Round 5
// baseline (2704.738 us; speedup 1.0000x reference)
//
#include <hip/hip_runtime.h>
#include <cstddef>

typedef __attribute__((__ext_vector_type__(8))) short bf16x8;
typedef __attribute__((__ext_vector_type__(4))) float f32x4;
typedef __attribute__((__ext_vector_type__(2))) float f32x2;

#define MFMA16(a, b, c) __builtin_amdgcn_mfma_f32_16x16x32_bf16((a), (b), (c), 0, 0, 0)

__device__ __forceinline__ unsigned short bf16_rne(float f) {
    unsigned int u = __float_as_uint(f);
    u += 0x7fffu + ((u >> 16) & 1u);
    return (unsigned short)(u >> 16);
}
__device__ __forceinline__ float bf16_to_f32(unsigned short h) {
    return __uint_as_float(((unsigned int)h) << 16);
}
// pack two f32 -> two bf16 (RNE) in one VALU op; lo = src0, hi = src1
__device__ __forceinline__ unsigned int pk_bf16(float lo, float hi) {
    unsigned int r;
    asm("v_cvt_pk_bf16_f32 %0, %1, %2" : "=v"(r) : "v"(lo), "v"(hi));
    return r;
}
// raw v_exp_f32: D = 2^x (trans op)
__device__ __forceinline__ float exp2_raw(float x) {
    float r;
    asm("v_exp_f32 %0, %1" : "=v"(r) : "v"(x));
    return r;
}
__device__ __forceinline__ f32x2 pk_fma(f32x2 a, f32x2 b, f32x2 c) {
    return __builtin_elementwise_fma(a, b, c);
}
// tanh on an f32x2 pair: tanh(x) = 1 - 2/(2^(2*log2e*x)+1)
__device__ __forceinline__ f32x2 tanh_pair(f32x2 x) {
    const f32x2 k2l2e = {2.88539008177793f, 2.88539008177793f};
    f32x2 t = x * k2l2e;
    f32x2 e;
    e.x = exp2_raw(t.x);
    e.y = exp2_raw(t.y);
    f32x2 ep1 = e + (f32x2){1.f, 1.f};
    f32x2 r;
    r.x = __builtin_amdgcn_rcpf(ep1.x);
    r.y = __builtin_amdgcn_rcpf(ep1.y);
    return pk_fma((f32x2){-2.f, -2.f}, r, (f32x2){1.f, 1.f});
}
// fused DPP add: v += dpp(v). GCNDPPCombine folds mov_dpp+add into v_add_f32_dpp.
template <int CTRL>
__device__ __forceinline__ float dpp_add(float v) {
    int t = __builtin_amdgcn_update_dpp(0, __float_as_int(v), CTRL, 0xF, 0xF, false);
    return v + __int_as_float(t);
}
// all-reduce (sum) across the 16 lanes of each quad-row
__device__ __forceinline__ float allred16(float v) {
    v = dpp_add<0xB1>(v);   // quad_perm [1,0,3,2]
    v = dpp_add<0x4E>(v);   // quad_perm [2,3,0,1]
    v = dpp_add<0x124>(v);  // row_ror:4
    v = dpp_add<0x128>(v);  // row_ror:8
    return v;
}
__device__ __forceinline__ float vc(f32x2 v, int c) { return c ? v.y : v.x; }

// One wave = 16 samples. MFMA 16x16x32 bf16 layouts (HW-verified, guide §3):
//   C/D: col = lane&15, row = (lane>>4)*4 + reg
//   A  : A[m = lane&15][k = (lane>>4)*8 + j], j=0..7
//   B  : B[k = (lane>>4)*8 + j][n = lane&15]
//
// R8 (on the R7 pk/JVP structure; resubmitted after infra failure):
//  * launch_bounds(256,4): R7 is latency-bound (VALUBusy fell 79->73 as inst
//    count dropped; occupancy 33%). The lean R7 state should fit the 128-reg
//    unified budget (R5's spill was the fat dual-transpose structure).
//  * Explicit lgkmcnt(0) drains REMOVED: same-wave DS ops execute in order,
//    so the WAR fence was free and the RAW write->read needs only data-return
//    waits, which the compiler inserts minimally (counted lgkmcnt) -> the 8
//    fwd MFMAs start while tangent-frag reads are still in flight.
__global__ __launch_bounds__(256, 4)
void cnf_mfma_kernel(const float* __restrict__ x,
                     const float* __restrict__ ctx,
                     const float* __restrict__ eps,
                     const float* __restrict__ W1,
                     const float* __restrict__ b1,
                     const float* __restrict__ W2,
                     const float* __restrict__ b2,
                     const float* __restrict__ W3,
                     const float* __restrict__ b3,
                     float* __restrict__ out,
                     int nb)
{
    // W2 fwd B-fragments, k-permuted by sigma, pre-packed per-lane
    __shared__ __align__(16) unsigned short sW2f[4096];
    // per-wave transpose buffer: 16 rows h1 + 16 rows t1, row stride 72 ushorts
    __shared__ __align__(16) unsigned short lds[4 * 32 * 72];

    const int tid  = threadIdx.x;
    const int lane = tid & 63;
    const int wv   = tid >> 6;
    const int l15  = lane & 15;
    const int quad = lane >> 4;
    unsigned short* tbH = &lds[wv * 32 * 72];
    unsigned short* tbT = tbH + 16 * 72;

    // ---- cooperative W2 fragment fill (fwd layout, k permuted by sigma) ----
    for (int idx = tid; idx < 4096; idx += 256) {
        int i = idx >> 6, c = idx & 63;
        int kp = (i & 15) * 4 + (i >> 4);  // sigma(i)
        sW2f[(((kp >> 5) * 4 + (c >> 4)) * 64 + ((kp >> 3) & 3) * 16 + (c & 15)) * 8 + (kp & 7)] =
            bf16_rne(W2[idx]);
    }
    __syncthreads();

    const int sBase = (blockIdx.x * 4 + wv) * 16;
    if (sBase >= nb) return;

    // ---- per-lane column constants, duplicated into f32x2 for pk ops ----
    f32x2 w1z0d[4], w1z1d[4], w1ttd[4], w30d[4], w31d[4];
    float b2c[4];
    #pragma unroll
    for (int t = 0; t < 4; ++t) {
        int col = t * 16 + l15;
        float a0 = W1[col], a1 = W1[64 + col], a2 = W1[66 * 64 + col];
        float a3 = W3[2 * col], a4 = W3[2 * col + 1];
        w1z0d[t] = (f32x2){a0, a0};
        w1z1d[t] = (f32x2){a1, a1};
        w1ttd[t] = (f32x2){a2, a2};
        w30d[t]  = (f32x2){a3, a3};
        w31d[t]  = (f32x2){a4, a4};
        b2c[t]   = b2[col];
    }
    const float b30 = b3[0], b31 = b3[1];

    // ---- c1 = b1 + ctx @ W1[2:66], via MFMA with hi/lo bf16 split ----
    f32x2 c1h[4][2];
    {
        bf16x8 ah[2], al[2];
        #pragma unroll
        for (int ks = 0; ks < 2; ++ks) {
            bf16x8 h_, l_;
            #pragma unroll
            for (int j = 0; j < 8; ++j) {
                float v = ctx[(size_t)(sBase + l15) * 64 + ks * 32 + quad * 8 + j];
                unsigned short hh = bf16_rne(v);
                h_[j] = (short)hh;
                l_[j] = (short)bf16_rne(v - bf16_to_f32(hh));
            }
            ah[ks] = h_; al[ks] = l_;
        }
        #pragma unroll
        for (int t = 0; t < 4; ++t) {
            f32x4 acc;
            float b1c = b1[t * 16 + l15];
            acc[0] = b1c; acc[1] = b1c; acc[2] = b1c; acc[3] = b1c;
            #pragma unroll
            for (int ks = 0; ks < 2; ++ks) {
                bf16x8 bh, bl;
                #pragma unroll
                for (int j = 0; j < 8; ++j) {
                    float v = W1[(size_t)(2 + ks * 32 + quad * 8 + j) * 64 + t * 16 + l15];
                    unsigned short hh = bf16_rne(v);
                    bh[j] = (short)hh;
                    bl[j] = (short)bf16_rne(v - bf16_to_f32(hh));
                }
                acc = MFMA16(ah[ks], bh, acc);
                acc = MFMA16(al[ks], bh, acc);
                acc = MFMA16(ah[ks], bl, acc);
            }
            c1h[t][0] = (f32x2){acc[0], acc[1]};
            c1h[t][1] = (f32x2){acc[2], acc[3]};
        }
    }

    // ---- z state as r-pairs (replicated across the 16 lanes of a quad) ----
    f32x2 z0p[2], z1p[2], lsump[2];
    #pragma unroll
    for (int rp = 0; rp < 2; ++rp) {
        const float* px = x + (size_t)(sBase + quad * 4 + rp * 2) * 2;
        z0p[rp] = (f32x2){px[0], px[2]};
        z1p[rp] = (f32x2){px[1], px[3]};
        lsump[rp] = (f32x2){0.f, 0.f};
    }

    const float hstep = -1.f / 9.f;

    // eps: current pair regs + one-stage-ahead prefetch; pointer walks by nb*2
    f32x2 e0p[2], e1p[2], e0np[2] = {{0.f,0.f},{0.f,0.f}}, e1np[2] = {{0.f,0.f},{0.f,0.f}};
    {
        const float* p = eps + (size_t)(sBase + quad * 4) * 2;
        float4 q0 = *(const float4*)(p);
        float4 q1 = *(const float4*)(p + 4);
        e0p[0] = (f32x2){q0.x, q0.z}; e1p[0] = (f32x2){q0.y, q0.w};
        e0p[1] = (f32x2){q1.x, q1.z}; e1p[1] = (f32x2){q1.y, q1.w};
    }
    const float* ep = eps + ((size_t)nb + sBase + quad * 4) * 2;
    const size_t estride = (size_t)nb * 2;

    #pragma unroll 1
    for (int k = 0; k < 9; ++k) {
        float ti = 1.f + (float)k * hstep;
        f32x2 ze0p[2], ze1p[2], zs0p[2], zs1p[2];
        #pragma unroll
        for (int rp = 0; rp < 2; ++rp) {
            ze0p[rp] = z0p[rp]; ze1p[rp] = z1p[rp];
            zs0p[rp] = (f32x2){0.f, 0.f}; zs1p[rp] = (f32x2){0.f, 0.f};
        }

        #pragma unroll 1
        for (int st = 0; st < 4; ++st) {
            // opaque zero: blocks LICM from hoisting the 8 W2-fragment
            // ds_read_b128s out of the loop (that would re-pin 64 VGPRs)
            int zo = 0;
            __asm__ volatile("" : "+v"(zo));
            const unsigned short* pf = sW2f + zo;

            float coef = (st == 0) ? 0.f : ((st == 3) ? 1.f : 0.5f);
            float tcur = ti + coef * hstep;
            f32x2 tcur2 = (f32x2){tcur, tcur};
            int stg = k * 4 + st;
            if (stg < 35) {
                float4 q0 = *(const float4*)(ep);
                float4 q1 = *(const float4*)(ep + 4);
                e0np[0] = (f32x2){q0.x, q0.z}; e1np[0] = (f32x2){q0.y, q0.w};
                e0np[1] = (f32x2){q1.x, q1.z}; e1np[1] = (f32x2){q1.y, q1.w};
            }
            ep += estride;

            // ---- layer 1 + JVP seed, r-pair packed; LDS write per half ----
            // (no explicit WAR fence: same-wave DS ops are in-order, and this
            // stage's writes are issued after last stage's frag reads)
            #pragma unroll
            for (int rp = 0; rp < 2; ++rp) {
                f32x2 hv[4], tv[4];
                #pragma unroll
                for (int t = 0; t < 4; ++t) {
                    f32x2 pre = c1h[t][rp];
                    pre = pk_fma(ze0p[rp], w1z0d[t], pre);
                    pre = pk_fma(ze1p[rp], w1z1d[t], pre);
                    pre = pk_fma(tcur2, w1ttd[t], pre);
                    f32x2 h = tanh_pair(pre);
                    hv[t] = h;
                    f32x2 ew = pk_fma(e1p[rp], w1z1d[t], e0p[rp] * w1z0d[t]);
                    tv[t] = ew * pk_fma(-h, h, (f32x2){1.f, 1.f});
                }
                #pragma unroll
                for (int c = 0; c < 2; ++c) {
                    int row = quad * 4 + rp * 2 + c;
                    uint2 hw, tw;
                    hw.x = pk_bf16(vc(hv[0], c), vc(hv[1], c));
                    hw.y = pk_bf16(vc(hv[2], c), vc(hv[3], c));
                    tw.x = pk_bf16(vc(tv[0], c), vc(tv[1], c));
                    tw.y = pk_bf16(vc(tv[2], c), vc(tv[3], c));
                    *(uint2*)&tbH[row * 72 + l15 * 4] = hw;
                    *(uint2*)&tbT[row * 72 + l15 * 4] = tw;
                }
            }
            // reads issued right after writes; same-wave DS in-order makes the
            // RAW safe, and the compiler inserts minimal counted lgkmcnt before
            // each MFMA use (af can start while tangent reads are in flight)
            bf16x8 a1k0 = *(const bf16x8*)&tbH[l15 * 72 + quad * 8];
            bf16x8 a1k1 = *(const bf16x8*)&tbH[l15 * 72 + 32 + quad * 8];
            bf16x8 atk0 = *(const bf16x8*)&tbT[l15 * 72 + quad * 8];
            bf16x8 atk1 = *(const bf16x8*)&tbT[l15 * 72 + 32 + quad * 8];

            // ---- layer 2 fwd + tangent: 16 MFMAs sharing B-fragments ----
            f32x2 f0pp[2] = {{0.f,0.f},{0.f,0.f}}, f1pp[2] = {{0.f,0.f},{0.f,0.f}};
            f32x2 dv0pp[2] = {{0.f,0.f},{0.f,0.f}}, dv1pp[2] = {{0.f,0.f},{0.f,0.f}};
            #pragma unroll
            for (int t = 0; t < 4; ++t) {
                bf16x8 bk0 = *(const bf16x8*)&pf[(t * 64 + lane) * 8];
                bf16x8 bk1 = *(const bf16x8*)&pf[((4 + t) * 64 + lane) * 8];
                f32x4 af; af[0] = b2c[t]; af[1] = b2c[t]; af[2] = b2c[t]; af[3] = b2c[t];
                af = MFMA16(a1k0, bk0, af);
                af = MFMA16(a1k1, bk1, af);
                f32x4 at_; at_[0] = 0.f; at_[1] = 0.f; at_[2] = 0.f; at_[3] = 0.f;
                at_ = MFMA16(atk0, bk0, at_);
                at_ = MFMA16(atk1, bk1, at_);
                #pragma unroll
                for (int rp = 0; rp < 2; ++rp) {
                    f32x2 afp = rp ? (f32x2){af[2], af[3]} : (f32x2){af[0], af[1]};
                    f32x2 atp = rp ? (f32x2){at_[2], at_[3]} : (f32x2){at_[0], at_[1]};
                    f32x2 h2 = tanh_pair(afp);
                    f0pp[rp] = pk_fma(h2, w30d[t], f0pp[rp]);
                    f1pp[rp] = pk_fma(h2, w31d[t], f1pp[rp]);
                    f32x2 t2v = atp * pk_fma(-h2, h2, (f32x2){1.f, 1.f});
                    dv0pp[rp] = pk_fma(t2v, w30d[t], dv0pp[rp]);
                    dv1pp[rp] = pk_fma(t2v, w31d[t], dv1pp[rp]);
                }
            }

            // ---- butterfly f only (dv deferred to kernel end, per-lane) ----
            #pragma unroll
            for (int rp = 0; rp < 2; ++rp) {
                f0pp[rp].x = allred16(f0pp[rp].x);
                f0pp[rp].y = allred16(f0pp[rp].y);
                f1pp[rp].x = allred16(f1pp[rp].x);
                f1pp[rp].y = allred16(f1pp[rp].y);
            }

            // ---- RK4 combine ----
            float wgt = (st == 1 || st == 2) ? 2.f : 1.f;
            f32x2 wgt2 = (f32x2){wgt, wgt};
            f32x2 wgtn2 = (f32x2){-wgt, -wgt};
            float cn = (st == 2) ? 1.f : 0.5f;
            f32x2 ch2 = (f32x2){cn * hstep, cn * hstep};
            #pragma unroll
            for (int rp = 0; rp < 2; ++rp) {
                f32x2 f0 = f0pp[rp] + (f32x2){b30, b30};
                f32x2 f1 = f1pp[rp] + (f32x2){b31, b31};
                zs0p[rp] = pk_fma(wgt2, f0, zs0p[rp]);
                zs1p[rp] = pk_fma(wgt2, f1, zs1p[rp]);
                f32x2 nd = pk_fma(dv1pp[rp], e1p[rp], dv0pp[rp] * e0p[rp]);
                lsump[rp] = pk_fma(nd, wgtn2, lsump[rp]);
                if (st < 3) {
                    ze0p[rp] = pk_fma(ch2, f0, z0p[rp]);
                    ze1p[rp] = pk_fma(ch2, f1, z1p[rp]);
                }
                e0p[rp] = e0np[rp]; e1p[rp] = e1np[rp];
            }
        }

        const float h6 = hstep * (1.f / 6.f);
        f32x2 h62 = (f32x2){h6, h6};
        #pragma unroll
        for (int rp = 0; rp < 2; ++rp) {
            z0p[rp] = pk_fma(h62, zs0p[rp], z0p[rp]);
            z1p[rp] = pk_fma(h62, zs1p[rp], z1p[rp]);
        }
    }

    // ---- deferred divergence reduction (once per kernel, not per stage) ----
    const float h6f = hstep * (1.f / 6.f);
    float lpv[4];
    lpv[0] = h6f * allred16(lsump[0].x);
    lpv[1] = h6f * allred16(lsump[0].y);
    lpv[2] = h6f * allred16(lsump[1].x);
    lpv[3] = h6f * allred16(lsump[1].y);

    if (l15 == 0) {
        #pragma unroll
        for (int rp = 0; rp < 2; ++rp) {
            int s = sBase + quad * 4 + rp * 2;
            out[2 * s]       = z0p[rp].x;
            out[2 * s + 1]   = z1p[rp].x;
            out[2 * s + 2]   = z0p[rp].y;
            out[2 * s + 3]   = z1p[rp].y;
            out[2 * nb + s]     = lpv[rp * 2];
            out[2 * nb + s + 1] = lpv[rp * 2 + 1];
        }
    }
}

extern "C" void kernel_launch(void* const* d_in, const int* in_sizes, int n_in,
                              void* d_out, int out_size, void* d_ws, size_t ws_size,
                              hipStream_t stream) {
    const float* x   = (const float*)d_in[0];
    const float* ctx = (const float*)d_in[1];
    const float* eps = (const float*)d_in[2];
    const float* W1  = (const float*)d_in[3];
    const float* b1  = (const float*)d_in[4];
    const float* W2  = (const float*)d_in[5];
    const float* b2  = (const float*)d_in[6];
    const float* W3  = (const float*)d_in[7];
    const float* b3  = (const float*)d_in[8];
    float* out = (float*)d_out;

    int nb = in_sizes[0] / 2;  // x is [B,2]
    int grid = (nb + 63) / 64; // 64 samples per 256-thread block (16 per wave)
    hipLaunchKernelGGL(cnf_mfma_kernel, dim3(grid), dim3(256), 0, stream,
                       x, ctx, eps, W1, b1, W2, b2, W3, b3, out, nb);
}

// Round 6
// 1422.044 us; speedup vs baseline: 1.9020x; 1.9020x over previous
//
#include <hip/hip_runtime.h>
#include <cstddef>

typedef __attribute__((__ext_vector_type__(8))) short bf16x8;
typedef __attribute__((__ext_vector_type__(4))) float f32x4;
typedef __attribute__((__ext_vector_type__(2))) float f32x2;

#define MFMA16(a, b, c) __builtin_amdgcn_mfma_f32_16x16x32_bf16((a), (b), (c), 0, 0, 0)

__device__ __forceinline__ unsigned short bf16_rne(float f) {
    unsigned int u = __float_as_uint(f);
    u += 0x7fffu + ((u >> 16) & 1u);
    return (unsigned short)(u >> 16);
}
__device__ __forceinline__ float bf16_to_f32(unsigned short h) {
    return __uint_as_float(((unsigned int)h) << 16);
}
// pack two f32 -> two bf16 (RNE) in one VALU op; lo = src0, hi = src1
__device__ __forceinline__ unsigned int pk_bf16(float lo, float hi) {
    unsigned int r;
    asm("v_cvt_pk_bf16_f32 %0, %1, %2" : "=v"(r) : "v"(lo), "v"(hi));
    return r;
}
// raw v_exp_f32: D = 2^x (trans op)
__device__ __forceinline__ float exp2_raw(float x) {
    float r;
    asm("v_exp_f32 %0, %1" : "=v"(r) : "v"(x));
    return r;
}
__device__ __forceinline__ f32x2 pk_fma(f32x2 a, f32x2 b, f32x2 c) {
    return __builtin_elementwise_fma(a, b, c);
}
// tanh on an f32x2 pair: tanh(x) = 1 - 2/(2^(2*log2e*x)+1)
__device__ __forceinline__ f32x2 tanh_pair(f32x2 x) {
    const f32x2 k2l2e = {2.88539008177793f, 2.88539008177793f};
    f32x2 t = x * k2l2e;
    f32x2 e;
    e.x = exp2_raw(t.x);
    e.y = exp2_raw(t.y);
    f32x2 ep1 = e + (f32x2){1.f, 1.f};
    f32x2 r;
    r.x = __builtin_amdgcn_rcpf(ep1.x);
    r.y = __builtin_amdgcn_rcpf(ep1.y);
    return pk_fma((f32x2){-2.f, -2.f}, r, (f32x2){1.f, 1.f});
}
// fused DPP add: v += dpp(v). GCNDPPCombine folds mov_dpp+add into v_add_f32_dpp.
template <int CTRL>
__device__ __forceinline__ float dpp_add(float v) {
    int t = __builtin_amdgcn_update_dpp(0, __float_as_int(v), CTRL, 0xF, 0xF, false);
    return v + __int_as_float(t);
}
// all-reduce (sum) across the 16 lanes of each quad-row
__device__ __forceinline__ float allred16(float v) {
    v = dpp_add<0xB1>(v);   // quad_perm [1,0,3,2]
    v = dpp_add<0x4E>(v);   // quad_perm [2,3,0,1]
    v = dpp_add<0x124>(v);  // row_ror:4
    v = dpp_add<0x128>(v);  // row_ror:8
    return v;
}
__device__ __forceinline__ float vc(f32x2 v, int c) { return c ? v.y : v.x; }

// One wave = 16 samples. MFMA 16x16x32 bf16 layouts (HW-verified, guide §3):
//   C/D: col = lane&15, row = (lane>>4)*4 + reg
//   A  : A[m = lane&15][k = (lane>>4)*8 + j], j=0..7
//   B  : B[k = (lane>>4)*8 + j][n = lane&15]
//
// R9 (back on the R7 (256,3) platform after R8's (256,4) re-spilled:
// VGPR clamped to 64, 9GB spill traffic, dur 2705 -> the ~150-reg live
// state structurally needs the 170 budget; 3 waves/SIMD is the ceiling):
//  * The two full `s_waitcnt lgkmcnt(0)` drains are REMOVED. Same-wave DS
//    ops execute in order in the LDS pipe, so the write->read RAW through
//    the transpose buffer needs no drain; the compiler inserts counted
//    lgkmcnt before each MFMA use of the read data. A single
//    sched_barrier(0) after the write loop pins compile-time program order
//    (rule #18: hipcc may otherwise hoist the per-lane "non-aliasing"
//    ds_reads above the ds_writes).
//  * Side effect: the 8 loop-invariant W2-frag ds_read_b128 are no longer
//    pinned behind a drain and can hoist to the stage top, overlapping
//    their latency with layer-1 VALU work.
__global__ __launch_bounds__(256, 3)
void cnf_mfma_kernel(const float* __restrict__ x,
                     const float* __restrict__ ctx,
                     const float* __restrict__ eps,
                     const float* __restrict__ W1,
                     const float* __restrict__ b1,
                     const float* __restrict__ W2,
                     const float* __restrict__ b2,
                     const float* __restrict__ W3,
                     const float* __restrict__ b3,
                     float* __restrict__ out,
                     int nb)
{
    // W2 fwd B-fragments, k-permuted by sigma, pre-packed per-lane
    __shared__ __align__(16) unsigned short sW2f[4096];
    // per-wave transpose buffer: 16 rows h1 + 16 rows t1, row stride 72 ushorts
    __shared__ __align__(16) unsigned short lds[4 * 32 * 72];

    const int tid  = threadIdx.x;
    const int lane = tid & 63;
    const int wv   = tid >> 6;
    const int l15  = lane & 15;
    const int quad = lane >> 4;
    unsigned short* tbH = &lds[wv * 32 * 72];
    unsigned short* tbT = tbH + 16 * 72;

    // ---- cooperative W2 fragment fill (fwd layout, k permuted by sigma) ----
    for (int idx = tid; idx < 4096; idx += 256) {
        int i = idx >> 6, c = idx & 63;
        int kp = (i & 15) * 4 + (i >> 4);  // sigma(i)
        sW2f[(((kp >> 5) * 4 + (c >> 4)) * 64 + ((kp >> 3) & 3) * 16 + (c & 15)) * 8 + (kp & 7)] =
            bf16_rne(W2[idx]);
    }
    __syncthreads();

    const int sBase = (blockIdx.x * 4 + wv) * 16;
    if (sBase >= nb) return;

    // ---- per-lane column constants, duplicated into f32x2 for pk ops ----
    f32x2 w1z0d[4], w1z1d[4], w1ttd[4], w30d[4], w31d[4];
    float b2c[4];
    #pragma unroll
    for (int t = 0; t < 4; ++t) {
        int col = t * 16 + l15;
        float a0 = W1[col], a1 = W1[64 + col], a2 = W1[66 * 64 + col];
        float a3 = W3[2 * col], a4 = W3[2 * col + 1];
        w1z0d[t] = (f32x2){a0, a0};
        w1z1d[t] = (f32x2){a1, a1};
        w1ttd[t] = (f32x2){a2, a2};
        w30d[t]  = (f32x2){a3, a3};
        w31d[t]  = (f32x2){a4, a4};
        b2c[t]   = b2[col];
    }
    const float b30 = b3[0], b31 = b3[1];

    // ---- c1 = b1 + ctx @ W1[2:66], via MFMA with hi/lo bf16 split ----
    f32x2 c1h[4][2];
    {
        bf16x8 ah[2], al[2];
        #pragma unroll
        for (int ks = 0; ks < 2; ++ks) {
            bf16x8 h_, l_;
            #pragma unroll
            for (int j = 0; j < 8; ++j) {
                float v = ctx[(size_t)(sBase + l15) * 64 + ks * 32 + quad * 8 + j];
                unsigned short hh = bf16_rne(v);
                h_[j] = (short)hh;
                l_[j] = (short)bf16_rne(v - bf16_to_f32(hh));
            }
            ah[ks] = h_; al[ks] = l_;
        }
        #pragma unroll
        for (int t = 0; t < 4; ++t) {
            f32x4 acc;
            float b1c = b1[t * 16 + l15];
            acc[0] = b1c; acc[1] = b1c; acc[2] = b1c; acc[3] = b1c;
            #pragma unroll
            for (int ks = 0; ks < 2; ++ks) {
                bf16x8 bh, bl;
                #pragma unroll
                for (int j = 0; j < 8; ++j) {
                    float v = W1[(size_t)(2 + ks * 32 + quad * 8 + j) * 64 + t * 16 + l15];
                    unsigned short hh = bf16_rne(v);
                    bh[j] = (short)hh;
                    bl[j] = (short)bf16_rne(v - bf16_to_f32(hh));
                }
                acc = MFMA16(ah[ks], bh, acc);
                acc = MFMA16(al[ks], bh, acc);
                acc = MFMA16(ah[ks], bl, acc);
            }
            c1h[t][0] = (f32x2){acc[0], acc[1]};
            c1h[t][1] = (f32x2){acc[2], acc[3]};
        }
    }

    // ---- z state as r-pairs (replicated across the 16 lanes of a quad) ----
    f32x2 z0p[2], z1p[2], lsump[2];
    #pragma unroll
    for (int rp = 0; rp < 2; ++rp) {
        const float* px = x + (size_t)(sBase + quad * 4 + rp * 2) * 2;
        z0p[rp] = (f32x2){px[0], px[2]};
        z1p[rp] = (f32x2){px[1], px[3]};
        lsump[rp] = (f32x2){0.f, 0.f};
    }

    const float hstep = -1.f / 9.f;

    // eps: current pair regs + one-stage-ahead prefetch; pointer walks by nb*2
    f32x2 e0p[2], e1p[2], e0np[2] = {{0.f,0.f},{0.f,0.f}}, e1np[2] = {{0.f,0.f},{0.f,0.f}};
    {
        const float* p = eps + (size_t)(sBase + quad * 4) * 2;
        float4 q0 = *(const float4*)(p);
        float4 q1 = *(const float4*)(p + 4);
        e0p[0] = (f32x2){q0.x, q0.z}; e1p[0] = (f32x2){q0.y, q0.w};
        e0p[1] = (f32x2){q1.x, q1.z}; e1p[1] = (f32x2){q1.y, q1.w};
    }
    const float* ep = eps + ((size_t)nb + sBase + quad * 4) * 2;
    const size_t estride = (size_t)nb * 2;

    #pragma unroll 1
    for (int k = 0; k < 9; ++k) {
        float ti = 1.f + (float)k * hstep;
        f32x2 ze0p[2], ze1p[2], zs0p[2], zs1p[2];
        #pragma unroll
        for (int rp = 0; rp < 2; ++rp) {
            ze0p[rp] = z0p[rp]; ze1p[rp] = z1p[rp];
            zs0p[rp] = (f32x2){0.f, 0.f}; zs1p[rp] = (f32x2){0.f, 0.f};
        }

        #pragma unroll 1
        for (int st = 0; st < 4; ++st) {
            // opaque zero: blocks LICM from hoisting the 8 W2-fragment
            // ds_read_b128s out of the loop (that would re-pin 64 VGPRs)
            int zo = 0;
            __asm__ volatile("" : "+v"(zo));
            const unsigned short* pf = sW2f + zo;

            float coef = (st == 0) ? 0.f : ((st == 3) ? 1.f : 0.5f);
            float tcur = ti + coef * hstep;
            f32x2 tcur2 = (f32x2){tcur, tcur};
            int stg = k * 4 + st;
            if (stg < 35) {
                float4 q0 = *(const float4*)(ep);
                float4 q1 = *(const float4*)(ep + 4);
                e0np[0] = (f32x2){q0.x, q0.z}; e1np[0] = (f32x2){q0.y, q0.w};
                e0np[1] = (f32x2){q1.x, q1.z}; e1np[1] = (f32x2){q1.y, q1.w};
            }
            ep += estride;

            // ---- layer 1 + JVP seed, r-pair packed; LDS write per half ----
            // (no runtime WAR fence needed: same-wave DS ops are in-order)
            #pragma unroll
            for (int rp = 0; rp < 2; ++rp) {
                f32x2 hv[4], tv[4];
                #pragma unroll
                for (int t = 0; t < 4; ++t) {
                    f32x2 pre = c1h[t][rp];
                    pre = pk_fma(ze0p[rp], w1z0d[t], pre);
                    pre = pk_fma(ze1p[rp], w1z1d[t], pre);
                    pre = pk_fma(tcur2, w1ttd[t], pre);
                    f32x2 h = tanh_pair(pre);
                    hv[t] = h;
                    f32x2 ew = pk_fma(e1p[rp], w1z1d[t], e0p[rp] * w1z0d[t]);
                    tv[t] = ew * pk_fma(-h, h, (f32x2){1.f, 1.f});
                }
                #pragma unroll
                for (int c = 0; c < 2; ++c) {
                    int row = quad * 4 + rp * 2 + c;
                    uint2 hw, tw;
                    hw.x = pk_bf16(vc(hv[0], c), vc(hv[1], c));
                    hw.y = pk_bf16(vc(hv[2], c), vc(hv[3], c));
                    tw.x = pk_bf16(vc(tv[0], c), vc(tv[1], c));
                    tw.y = pk_bf16(vc(tv[2], c), vc(tv[3], c));
                    *(uint2*)&tbH[row * 72 + l15 * 4] = hw;
                    *(uint2*)&tbT[row * 72 + l15 * 4] = tw;
                }
            }
            // pin compile-time order: all transpose ds_writes above the
            // ds_reads below (HW pipe order + counted lgkmcnt do the rest;
            // a full lgkmcnt(0) drain here cost ~100+ cyc/stage in R7)
            __builtin_amdgcn_sched_barrier(0);
            bf16x8 a1k0 = *(const bf16x8*)&tbH[l15 * 72 + quad * 8];
            bf16x8 a1k1 = *(const bf16x8*)&tbH[l15 * 72 + 32 + quad * 8];
            bf16x8 atk0 = *(const bf16x8*)&tbT[l15 * 72 + quad * 8];
            bf16x8 atk1 = *(const bf16x8*)&tbT[l15 * 72 + 32 + quad * 8];

            // ---- layer 2 fwd + tangent: 16 MFMAs sharing B-fragments ----
            f32x2 f0pp[2] = {{0.f,0.f},{0.f,0.f}}, f1pp[2] = {{0.f,0.f},{0.f,0.f}};
            f32x2 dv0pp[2] = {{0.f,0.f},{0.f,0.f}}, dv1pp[2] = {{0.f,0.f},{0.f,0.f}};
            #pragma unroll
            for (int t = 0; t < 4; ++t) {
                bf16x8 bk0 = *(const bf16x8*)&pf[(t * 64 + lane) * 8];
                bf16x8 bk1 = *(const bf16x8*)&pf[((4 + t) * 64 + lane) * 8];
                f32x4 af; af[0] = b2c[t]; af[1] = b2c[t]; af[2] = b2c[t]; af[3] = b2c[t];
                af = MFMA16(a1k0, bk0, af);
                af = MFMA16(a1k1, bk1, af);
                f32x4 at_; at_[0] = 0.f; at_[1] = 0.f; at_[2] = 0.f; at_[3] = 0.f;
                at_ = MFMA16(atk0, bk0, at_);
                at_ = MFMA16(atk1, bk1, at_);
                #pragma unroll
                for (int rp = 0; rp < 2; ++rp) {
                    f32x2 afp = rp ? (f32x2){af[2], af[3]} : (f32x2){af[0], af[1]};
                    f32x2 atp = rp ? (f32x2){at_[2], at_[3]} : (f32x2){at_[0], at_[1]};
                    f32x2 h2 = tanh_pair(afp);
                    f0pp[rp] = pk_fma(h2, w30d[t], f0pp[rp]);
                    f1pp[rp] = pk_fma(h2, w31d[t], f1pp[rp]);
                    f32x2 t2v = atp * pk_fma(-h2, h2, (f32x2){1.f, 1.f});
                    dv0pp[rp] = pk_fma(t2v, w30d[t], dv0pp[rp]);
                    dv1pp[rp] = pk_fma(t2v, w31d[t], dv1pp[rp]);
                }
            }

            // ---- butterfly f only (dv deferred to kernel end, per-lane) ----
            #pragma unroll
            for (int rp = 0; rp < 2; ++rp) {
                f0pp[rp].x = allred16(f0pp[rp].x);
                f0pp[rp].y = allred16(f0pp[rp].y);
                f1pp[rp].x = allred16(f1pp[rp].x);
                f1pp[rp].y = allred16(f1pp[rp].y);
            }

            // ---- RK4 combine ----
            float wgt = (st == 1 || st == 2) ? 2.f : 1.f;
            f32x2 wgt2 = (f32x2){wgt, wgt};
            f32x2 wgtn2 = (f32x2){-wgt, -wgt};
            float cn = (st == 2) ? 1.f : 0.5f;
            f32x2 ch2 = (f32x2){cn * hstep, cn * hstep};
            #pragma unroll
            for (int rp = 0; rp < 2; ++rp) {
                f32x2 f0 = f0pp[rp] + (f32x2){b30, b30};
                f32x2 f1 = f1pp[rp] + (f32x2){b31, b31};
                zs0p[rp] = pk_fma(wgt2, f0, zs0p[rp]);
                zs1p[rp] = pk_fma(wgt2, f1, zs1p[rp]);
                f32x2 nd = pk_fma(dv1pp[rp], e1p[rp], dv0pp[rp] * e0p[rp]);
                lsump[rp] = pk_fma(nd, wgtn2, lsump[rp]);
                if (st < 3) {
                    ze0p[rp] = pk_fma(ch2, f0, z0p[rp]);
                    ze1p[rp] = pk_fma(ch2, f1, z1p[rp]);
                }
                e0p[rp] = e0np[rp]; e1p[rp] = e1np[rp];
            }
        }

        const float h6 = hstep * (1.f / 6.f);
        f32x2 h62 = (f32x2){h6, h6};
        #pragma unroll
        for (int rp = 0; rp < 2; ++rp) {
            z0p[rp] = pk_fma(h62, zs0p[rp], z0p[rp]);
            z1p[rp] = pk_fma(h62, zs1p[rp], z1p[rp]);
        }
    }

    // ---- deferred divergence reduction (once per kernel, not per stage) ----
    const float h6f = hstep * (1.f / 6.f);
    float lpv[4];
    lpv[0] = h6f * allred16(lsump[0].x);
    lpv[1] = h6f * allred16(lsump[0].y);
    lpv[2] = h6f * allred16(lsump[1].x);
    lpv[3] = h6f * allred16(lsump[1].y);

    if (l15 == 0) {
        #pragma unroll
        for (int rp = 0; rp < 2; ++rp) {
            int s = sBase + quad * 4 + rp * 2;
            out[2 * s]       = z0p[rp].x;
            out[2 * s + 1]   = z1p[rp].x;
            out[2 * s + 2]   = z0p[rp].y;
            out[2 * s + 3]   = z1p[rp].y;
            out[2 * nb + s]     = lpv[rp * 2];
            out[2 * nb + s + 1] = lpv[rp * 2 + 1];
        }
    }
}

extern "C" void kernel_launch(void* const* d_in, const int* in_sizes, int n_in,
                              void* d_out, int out_size, void* d_ws, size_t ws_size,
                              hipStream_t stream) {
    const float* x   = (const float*)d_in[0];
    const float* ctx = (const float*)d_in[1];
    const float* eps = (const float*)d_in[2];
    const float* W1  = (const float*)d_in[3];
    const float* b1  = (const float*)d_in[4];
    const float* W2  = (const float*)d_in[5];
    const float* b2  = (const float*)d_in[6];
    const float* W3  = (const float*)d_in[7];
    const float* b3  = (const float*)d_in[8];
    float* out = (float*)d_out;

    int nb = in_sizes[0] / 2;  // x is [B,2]
    int grid = (nb + 63) / 64; // 64 samples per 256-thread block (16 per wave)
    hipLaunchKernelGGL(cnf_mfma_kernel, dim3(grid), dim3(256), 0, stream,
                       x, ctx, eps, W1, b1, W2, b2, W3, b3, out, nb);
}